// Round 4
// baseline (118.267 us; speedup 1.0000x reference)
//
#include <hip/hip_runtime.h>
#include <hip/hip_fp16.h>
#include <math.h>

#define NN 1024
#define CC 200
#define AA 256
#define CT 13            // c-tiles (B/n side)
#define KC 32            // k-chunks (8 a's each)

static constexpr float P_EXP = 0.8f;
static constexpr float Q_EXP = 2.0f;
static constexpr float EPS_C = 0.01f;

typedef __attribute__((ext_vector_type(8))) _Float16 half8;
typedef __attribute__((ext_vector_type(2))) _Float16 half2v;
typedef __attribute__((ext_vector_type(4))) float f32x4;

// ---------------- prep: W->fp16 (208 rows, zero pad) + counts ----------------
__global__ void k_prep(const float* __restrict__ W, const int* __restrict__ lab,
                       _Float16* __restrict__ Whf, float* __restrict__ accv){
  if (blockIdx.x == 52){
    __shared__ int cnt[CC];
    int t = threadIdx.x;
    for (int i = t; i < CC; i += 256) cnt[i] = 0;
    __syncthreads();
    for (int n = t; n < NN; n += 256) atomicAdd(&cnt[lab[n]], 1);
    __syncthreads();
    for (int i = t; i < CC; i += 256) accv[i] = fmaxf((float)cnt[i], 1.0f);
    return;
  }
  int idx = (blockIdx.x * 256 + threadIdx.x) * 4;   // 52 blocks cover 208*256
  if (idx >= 208 * AA) return;
  float4 w = make_float4(0.f, 0.f, 0.f, 0.f);
  if (idx < CC * AA) w = *(const float4*)(W + idx);
  Whf[idx + 0] = (_Float16)w.x;
  Whf[idx + 1] = (_Float16)w.y;
  Whf[idx + 2] = (_Float16)w.z;
  Whf[idx + 3] = (_Float16)w.w;
}

// ---------------- deep-K GEMM: T1[l,c] = sum_ab W[c,a]W[c,b] CV[l,ab] ----------------
// grid (13 l-tiles, 32 k-chunks) x 256 (4 waves). Wave w owns a = kc*8+2w, +1.
// A-frag (m=l): CV[l, a*256+b] contiguous; B-frag (n=c): W[c,a]*W[c,b] via pk_mul.
// Fused: u[l,a] = sum_b CV*W[l,b] (regs), v[l,b] = sum_a CV*W[l,a] (LDS atomics).
__global__ __launch_bounds__(256) void k_quad(
    const float* __restrict__ W, const _Float16* __restrict__ Whf,
    const float* __restrict__ CV,
    float* __restrict__ qbuf, float* __restrict__ ug, float* __restrict__ vg)
{
  const int ltile = blockIdx.x;
  const int kc    = blockIdx.y;
  const int wid   = threadIdx.x >> 6;
  const int lane  = threadIdx.x & 63;
  const int lrow  = lane & 15;
  const int kgrp  = lane >> 4;

  __shared__ float vlds[16][AA + 8];
  for (int i = threadIdx.x; i < 16 * (AA + 8); i += 256) ((float*)vlds)[i] = 0.f;
  __syncthreads();

  const int l_cv = min(ltile * 16 + lrow, CC - 1);   // A-side row (clamped)
  const int a0   = kc * 8 + wid * 2;

  const float wla0 = W[l_cv * AA + a0];
  const float wla1 = W[l_cv * AA + a0 + 1];

  half2v wa2[CT];
  #pragma unroll
  for (int ct = 0; ct < CT; ++ct)
    wa2[ct] = *(const half2v*)(Whf + (ct * 16 + lrow) * AA + a0);

  f32x4 acc[CT];
  #pragma unroll
  for (int ct = 0; ct < CT; ++ct) acc[ct] = (f32x4){0.f, 0.f, 0.f, 0.f};

  float uacc0 = 0.f, uacc1 = 0.f;
  const size_t cvbase = (size_t)l_cv * AA * AA;

  #pragma unroll
  for (int bs = 0; bs < 8; ++bs){
    const int boff = bs * 32 + kgrp * 8;
    const float* p0 = CV + cvbase + (size_t)(a0    ) * AA + boff;
    const float* p1 = CV + cvbase + (size_t)(a0 + 1) * AA + boff;
    float4 c00 = *(const float4*)(p0), c01 = *(const float4*)(p0 + 4);
    float4 c10 = *(const float4*)(p1), c11 = *(const float4*)(p1 + 4);
    float4 w0  = *(const float4*)(W + l_cv * AA + boff);
    float4 w1  = *(const float4*)(W + l_cv * AA + boff + 4);

    // u partials (this lane's b-slice)
    uacc0 += c00.x*w0.x + c00.y*w0.y + c00.z*w0.z + c00.w*w0.w
           + c01.x*w1.x + c01.y*w1.y + c01.z*w1.z + c01.w*w1.w;
    uacc1 += c10.x*w0.x + c10.y*w0.y + c10.z*w0.z + c10.w*w0.w
           + c11.x*w1.x + c11.y*w1.y + c11.z*w1.z + c11.w*w1.w;

    // v partials: both a's combined, 8 LDS atomics
    atomicAdd(&vlds[lrow][boff + 0], c00.x*wla0 + c10.x*wla1);
    atomicAdd(&vlds[lrow][boff + 1], c00.y*wla0 + c10.y*wla1);
    atomicAdd(&vlds[lrow][boff + 2], c00.z*wla0 + c10.z*wla1);
    atomicAdd(&vlds[lrow][boff + 3], c00.w*wla0 + c10.w*wla1);
    atomicAdd(&vlds[lrow][boff + 4], c01.x*wla0 + c11.x*wla1);
    atomicAdd(&vlds[lrow][boff + 5], c01.y*wla0 + c11.y*wla1);
    atomicAdd(&vlds[lrow][boff + 6], c01.z*wla0 + c11.z*wla1);
    atomicAdd(&vlds[lrow][boff + 7], c01.w*wla0 + c11.w*wla1);

    // A-frags (CV -> fp16)
    half8 af0, af1;
    af0[0]=(_Float16)c00.x; af0[1]=(_Float16)c00.y; af0[2]=(_Float16)c00.z; af0[3]=(_Float16)c00.w;
    af0[4]=(_Float16)c01.x; af0[5]=(_Float16)c01.y; af0[6]=(_Float16)c01.z; af0[7]=(_Float16)c01.w;
    af1[0]=(_Float16)c10.x; af1[1]=(_Float16)c10.y; af1[2]=(_Float16)c10.z; af1[3]=(_Float16)c10.w;
    af1[4]=(_Float16)c11.x; af1[5]=(_Float16)c11.y; af1[6]=(_Float16)c11.z; af1[7]=(_Float16)c11.w;

    #pragma unroll
    for (int ct = 0; ct < CT; ++ct){
      half8 wb = *(const half8*)(Whf + (ct * 16 + lrow) * AA + boff);
      half8 bv0 = wb * wa2[ct].x;            // W[c,a0]   * W[c,b-slice]
      half8 bv1 = wb * wa2[ct].y;            // W[c,a0+1] * W[c,b-slice]
      acc[ct] = __builtin_amdgcn_mfma_f32_16x16x32_f16(af0, bv0, acc[ct], 0, 0, 0);
      acc[ct] = __builtin_amdgcn_mfma_f32_16x16x32_f16(af1, bv1, acc[ct], 0, 0, 0);
    }
  }

  // u: reduce across kgrp lanes, exclusive store
  uacc0 += __shfl_xor(uacc0, 16); uacc0 += __shfl_xor(uacc0, 32);
  uacc1 += __shfl_xor(uacc1, 16); uacc1 += __shfl_xor(uacc1, 32);
  const int l_u = ltile * 16 + lrow;
  if (kgrp == 0 && l_u < CC){
    ug[l_u * AA + a0]     = uacc0;
    ug[l_u * AA + a0 + 1] = uacc1;
  }

  __syncthreads();
  // v flush
  for (int i = threadIdx.x; i < 16 * AA; i += 256){
    int r = i >> 8, b = i & 255;
    int lg = ltile * 16 + r;
    if (lg < CC) atomicAdd(&vg[lg * AA + b], vlds[r][b]);
  }

  // T1 partial write: D row = l (kgrp*4+jj), col = c (lrow)
  #pragma unroll
  for (int ct = 0; ct < CT; ++ct){
    int c = ct * 16 + lrow;
    if (c < CC){
      #pragma unroll
      for (int jj = 0; jj < 4; ++jj){
        int l = ltile * 16 + kgrp * 4 + jj;
        if (l < CC) atomicAdd(&qbuf[l * CC + c], acc[ct][jj]);
      }
    }
  }
}

// ---------------- combine: tbl = lam*(0.5*T1 + w_c.g_l + const_l) ----------------
__global__ __launch_bounds__(256) void k_combine(
    const float* __restrict__ W, const float* __restrict__ ms,
    const float* __restrict__ mtg, const float* __restrict__ lamp,
    float* __restrict__ qtbl, const float* __restrict__ ug,
    const float* __restrict__ vg)
{
  const int l = blockIdx.x;
  const int t = threadIdx.x;
  __shared__ float gsh[AA];
  __shared__ float red[256];

  float u  = ug[l * AA + t];
  float v  = vg[l * AA + t];
  float dm = mtg[l * AA + t] - ms[l * AA + t];
  float wl = W[l * AA + t];
  gsh[t] = dm - 0.5f * (u + v);
  red[t] = wl * (0.5f * u - dm);        // sums to 0.5*T4 - wl.dm
  __syncthreads();
  for (int o = 128; o; o >>= 1){ if (t < o) red[t] += red[t + o]; __syncthreads(); }
  const float cl  = red[0];
  const float lam = lamp[0];

  if (t < CC){
    const float* wc = W + t * AA;
    float d0 = 0.f, d1 = 0.f, d2 = 0.f, d3 = 0.f;
    #pragma unroll 8
    for (int a = 0; a < AA; a += 4){
      float4 w4 = *(const float4*)(wc + a);
      d0 = fmaf(w4.x, gsh[a + 0], d0);
      d1 = fmaf(w4.y, gsh[a + 1], d1);
      d2 = fmaf(w4.z, gsh[a + 2], d2);
      d3 = fmaf(w4.w, gsh[a + 3], d3);
    }
    qtbl[l * CC + t] = lam * (0.5f * qtbl[l * CC + t] + (d0 + d1) + (d2 + d3) + cl);
  }
}

// ---------------- per-row seesaw loss ----------------
__global__ __launch_bounds__(64) void k_rows(
    const float* __restrict__ ys, const int* __restrict__ lab,
    const float* __restrict__ accv, const float* __restrict__ tbl,
    float* __restrict__ nll)
{
  const int n    = blockIdx.x;
  const int lane = threadIdx.x;
  const int l    = lab[n];
  const float acc_l = accv[l];
  const float log_acc_l = logf(acc_l);

  float z[4];
  float m = -1e30f;
  #pragma unroll
  for (int k = 0; k < 4; k++){
    int cidx = k * 64 + lane;
    float zz = (cidx < CC) ? (ys[n * CC + cidx] + tbl[l * CC + cidx]) : -1e30f;
    z[k] = zz;
    m = fmaxf(m, zz);
  }
  for (int o = 32; o; o >>= 1) m = fmaxf(m, __shfl_xor(m, o));

  float se = 0.f;
  #pragma unroll
  for (int k = 0; k < 4; k++){
    int cidx = k * 64 + lane;
    if (cidx < CC) se += expf(z[k] - m);
  }
  for (int o = 32; o; o >>= 1) se += __shfl_xor(se, o);
  const float L0 = m + logf(se);

  const int kl = l >> 6, ll = l & 63;
  float zsel = (kl == 0) ? z[0] : (kl == 1 ? z[1] : (kl == 2 ? z[2] : z[3]));
  const float zl = __shfl(zsel, ll);
  const float logden = fmaxf(zl - L0, logf(EPS_C));

  float lg[4];
  float m2 = -1e30f;
  #pragma unroll
  for (int k = 0; k < 4; k++){
    int cidx = k * 64 + lane;
    float lz = -1e30f;
    if (cidx < CC){
      lz = z[k];
      if (cidx != l){
        float lratio = (z[k] - L0) - logden;
        float lcomp  = (lratio > 0.f) ? Q_EXP * lratio : 0.f;
        float accc   = accv[cidx];
        float lmit   = (accc < acc_l) ? P_EXP * (logf(accc) - log_acc_l) : 0.f;
        lz += lcomp + lmit;
      }
    }
    lg[k] = lz;
    m2 = fmaxf(m2, lz);
  }
  for (int o = 32; o; o >>= 1) m2 = fmaxf(m2, __shfl_xor(m2, o));
  float se2 = 0.f;
  #pragma unroll
  for (int k = 0; k < 4; k++){
    int cidx = k * 64 + lane;
    if (cidx < CC) se2 += expf(lg[k] - m2);
  }
  for (int o = 32; o; o >>= 1) se2 += __shfl_xor(se2, o);
  const float L1 = m2 + logf(se2);

  if (lane == 0) nll[n] = L1 - zl;
}

// ---------------- mean ----------------
__global__ void k_mean(const float* __restrict__ nll, float* __restrict__ out){
  __shared__ float s[256];
  int t = threadIdx.x;
  float v = 0.f;
  for (int i = t; i < NN; i += 256) v += nll[i];
  s[t] = v; __syncthreads();
  for (int o = 128; o; o >>= 1){ if (t < o) s[t] += s[t + o]; __syncthreads(); }
  if (t == 0) out[0] = s[0] / (float)NN;
}

extern "C" void kernel_launch(void* const* d_in, const int* in_sizes, int n_in,
                              void* d_out, int out_size, void* d_ws, size_t ws_size,
                              hipStream_t stream) {
  const float* W   = (const float*)d_in[0];
  const float* ys  = (const float*)d_in[2];
  const int*   lab = (const int*)  d_in[3];
  const float* lam = (const float*)d_in[4];
  const float* ms  = (const float*)d_in[5];
  const float* mt  = (const float*)d_in[6];
  const float* CV  = (const float*)d_in[7];

  float* ws   = (float*)d_ws;
  float* qtbl = ws;                          // 40000 (T1 partial, then tbl in-place)
  float* ug   = ws + 40000;                  // 51200
  float* vg   = ws + 91200;                  // 51200
  float* accv = ws + 142400;                 // 256
  float* nll  = ws + 142656;                 // 1024
  _Float16* Whf = (_Float16*)(ws + 143680);  // 208*256 fp16
  float* out  = (float*)d_out;

  hipMemsetAsync(ws, 0, 142400 * sizeof(float), stream);  // qtbl+ug+vg
  k_prep   <<<53, 256, 0, stream>>>(W, lab, Whf, accv);
  dim3 gq(13, KC);
  k_quad   <<<gq, 256, 0, stream>>>(W, Whf, CV, qtbl, ug, vg);
  k_combine<<<CC, 256, 0, stream>>>(W, ms, mt, lam, qtbl, ug, vg);
  k_rows   <<<NN, 64, 0, stream>>>(ys, lab, accv, qtbl, nll);
  k_mean   <<<1, 256, 0, stream>>>(nll, out);
}

// Round 5
// 106.638 us; speedup vs baseline: 1.1090x; 1.1090x over previous
//
#include <hip/hip_runtime.h>
#include <hip/hip_fp16.h>
#include <math.h>

#define NN 1024
#define CC 200
#define AA 256

static constexpr float P_EXP = 0.8f;
static constexpr float Q_EXP = 2.0f;
static constexpr float EPS_C = 0.01f;

typedef __attribute__((ext_vector_type(8))) _Float16 half8;
typedef __attribute__((ext_vector_type(4))) _Float16 half4v;
typedef __attribute__((ext_vector_type(4))) float f32x4;

// ---------------- prep: W->fp16 (208 rows, zero pad) + counts ----------------
__global__ void k_prep(const float* __restrict__ W, const int* __restrict__ lab,
                       _Float16* __restrict__ Whf, float* __restrict__ accv){
  if (blockIdx.x == 52){
    __shared__ int cnt[CC];
    int t = threadIdx.x;
    for (int i = t; i < CC; i += 256) cnt[i] = 0;
    __syncthreads();
    for (int n = t; n < NN; n += 256) atomicAdd(&cnt[lab[n]], 1);
    __syncthreads();
    for (int i = t; i < CC; i += 256) accv[i] = fmaxf((float)cnt[i], 1.0f);
    return;
  }
  int idx = (blockIdx.x * 256 + threadIdx.x) * 4;
  if (idx >= 208 * AA) return;
  float4 w = make_float4(0.f, 0.f, 0.f, 0.f);
  if (idx < CC * AA) w = *(const float4*)(W + idx);
  Whf[idx + 0] = (_Float16)w.x;
  Whf[idx + 1] = (_Float16)w.y;
  Whf[idx + 2] = (_Float16)w.z;
  Whf[idx + 3] = (_Float16)w.w;
}

// ---------------- quadratic form + shift: all-MFMA, no shuffles ----------------
// grid (200 l, 4 a-quarters) x 256 (4 waves). Wave handles ct = wid,wid+4,...
// MFMA1: M'[a,c] = sum_b CV_l[a,b] * E[c,b]     (per a-tile, K=b=256)
// MFMA2: D2[c',c] += sum_a E[c',a] * M'[a,c]  (+ E.(2dm) broadcast for shift)
// diag(D2) -> tbl via predicated atomicAdd.  tbl += lam*0.5*diag.
__global__ __launch_bounds__(256) void k_quad(
    const _Float16* __restrict__ Whf, const float* __restrict__ CV,
    const float* __restrict__ ms, const float* __restrict__ mtg,
    const float* __restrict__ lamp, float* __restrict__ tbl)
{
  const int l    = blockIdx.x;
  const int aq   = blockIdx.y;          // a-quarter: 4 a-tiles of 16
  const int wid  = threadIdx.x >> 6;
  const int lane = threadIdx.x & 63;
  const int lrow = lane & 15;
  const int kgrp = lane >> 4;

  // Wl b-frags (for E1 = Wc - Wl along b)
  half8 wl1[8];
  #pragma unroll
  for (int kt = 0; kt < 8; ++kt)
    wl1[kt] = *(const half8*)(Whf + l * AA + kt * 32 + kgrp * 8);

  f32x4 D2[4];
  #pragma unroll
  for (int i = 0; i < 4; ++i) D2[i] = (f32x4){0.f, 0.f, 0.f, 0.f};

  const size_t cvbase = (size_t)l * AA * AA;

  #pragma unroll
  for (int at = 0; at < 4; ++at){
    const int atg  = aq * 4 + at;
    const int arow = atg * 16 + lrow;        // CV row for A1-frag

    // A1-frags: CV[l, arow, b-slices] -> fp16
    half8 cvf[8];
    #pragma unroll
    for (int kt = 0; kt < 8; ++kt){
      const float* p = CV + cvbase + (size_t)arow * AA + kt * 32 + kgrp * 8;
      float4 v0 = *(const float4*)(p);
      float4 v1 = *(const float4*)(p + 4);
      half8 h;
      h[0]=(_Float16)v0.x; h[1]=(_Float16)v0.y; h[2]=(_Float16)v0.z; h[3]=(_Float16)v0.w;
      h[4]=(_Float16)v1.x; h[5]=(_Float16)v1.y; h[6]=(_Float16)v1.z; h[7]=(_Float16)v1.w;
      cvf[kt] = h;
    }

    // a-slice frags for MFMA2 (k = atg*16 + kgrp*4 + j)
    const int asl = atg * 16 + kgrp * 4;
    half4v wl2 = *(const half4v*)(Whf + l * AA + asl);
    float4 dmt = *(const float4*)(mtg + l * AA + asl);
    float4 dms = *(const float4*)(ms  + l * AA + asl);
    half4v dmf;
    dmf[0] = (_Float16)(2.f * (dmt.x - dms.x));
    dmf[1] = (_Float16)(2.f * (dmt.y - dms.y));
    dmf[2] = (_Float16)(2.f * (dmt.z - dms.z));
    dmf[3] = (_Float16)(2.f * (dmt.w - dms.w));

    int cti = 0;
    for (int ct = wid; ct < 13; ct += 4, ++cti){
      const int crow = ct * 16 + lrow;

      f32x4 acc1 = {0.f, 0.f, 0.f, 0.f};
      #pragma unroll
      for (int kt = 0; kt < 8; ++kt){
        half8 wcf = *(const half8*)(Whf + crow * AA + kt * 32 + kgrp * 8);
        half8 e1  = wcf - wl1[kt];
        acc1 = __builtin_amdgcn_mfma_f32_16x16x32_f16(cvf[kt], e1, acc1, 0, 0, 0);
      }

      // B2 = M' tile (already in B-frag layout), A2 = E a-slice
      half4v b2;
      b2[0]=(_Float16)acc1[0]; b2[1]=(_Float16)acc1[1];
      b2[2]=(_Float16)acc1[2]; b2[3]=(_Float16)acc1[3];
      half4v wc2 = *(const half4v*)(Whf + crow * AA + asl);
      half4v e2  = wc2 - wl2;
      D2[cti] = __builtin_amdgcn_mfma_f32_16x16x16f16(e2, b2,  D2[cti], 0, 0, 0);
      D2[cti] = __builtin_amdgcn_mfma_f32_16x16x16f16(e2, dmf, D2[cti], 0, 0, 0);
    }
  }

  // diag extraction: lane holds D2[c'=kgrp*4+jj][c=lrow]; diag where kgrp*4+jj==lrow
  const float lam = lamp[0];
  int cti = 0;
  for (int ct = wid; ct < 13; ct += 4, ++cti){
    const int c = ct * 16 + lrow;
    if (c < CC && (lrow >> 2) == kgrp){
      const int jj = lrow & 3;
      float d = (jj == 0) ? D2[cti][0] : (jj == 1) ? D2[cti][1]
              : (jj == 2) ? D2[cti][2] : D2[cti][3];
      atomicAdd(&tbl[l * CC + c], 0.5f * lam * d);
    }
  }
}

// ---------------- per-row seesaw loss ----------------
__global__ __launch_bounds__(64) void k_rows(
    const float* __restrict__ ys, const int* __restrict__ lab,
    const float* __restrict__ accv, const float* __restrict__ tbl,
    float* __restrict__ nll)
{
  const int n    = blockIdx.x;
  const int lane = threadIdx.x;
  const int l    = lab[n];
  const float acc_l = accv[l];
  const float log_acc_l = logf(acc_l);

  float z[4];
  float m = -1e30f;
  #pragma unroll
  for (int k = 0; k < 4; k++){
    int cidx = k * 64 + lane;
    float zz = (cidx < CC) ? (ys[n * CC + cidx] + tbl[l * CC + cidx]) : -1e30f;
    z[k] = zz;
    m = fmaxf(m, zz);
  }
  for (int o = 32; o; o >>= 1) m = fmaxf(m, __shfl_xor(m, o));

  float se = 0.f;
  #pragma unroll
  for (int k = 0; k < 4; k++){
    int cidx = k * 64 + lane;
    if (cidx < CC) se += expf(z[k] - m);
  }
  for (int o = 32; o; o >>= 1) se += __shfl_xor(se, o);
  const float L0 = m + logf(se);

  const int kl = l >> 6, ll = l & 63;
  float zsel = (kl == 0) ? z[0] : (kl == 1 ? z[1] : (kl == 2 ? z[2] : z[3]));
  const float zl = __shfl(zsel, ll);
  const float logden = fmaxf(zl - L0, logf(EPS_C));

  float lg[4];
  float m2 = -1e30f;
  #pragma unroll
  for (int k = 0; k < 4; k++){
    int cidx = k * 64 + lane;
    float lz = -1e30f;
    if (cidx < CC){
      lz = z[k];
      if (cidx != l){
        float lratio = (z[k] - L0) - logden;
        float lcomp  = (lratio > 0.f) ? Q_EXP * lratio : 0.f;
        float accc   = accv[cidx];
        float lmit   = (accc < acc_l) ? P_EXP * (logf(accc) - log_acc_l) : 0.f;
        lz += lcomp + lmit;
      }
    }
    lg[k] = lz;
    m2 = fmaxf(m2, lz);
  }
  for (int o = 32; o; o >>= 1) m2 = fmaxf(m2, __shfl_xor(m2, o));
  float se2 = 0.f;
  #pragma unroll
  for (int k = 0; k < 4; k++){
    int cidx = k * 64 + lane;
    if (cidx < CC) se2 += expf(lg[k] - m2);
  }
  for (int o = 32; o; o >>= 1) se2 += __shfl_xor(se2, o);
  const float L1 = m2 + logf(se2);

  if (lane == 0) nll[n] = L1 - zl;
}

// ---------------- mean ----------------
__global__ void k_mean(const float* __restrict__ nll, float* __restrict__ out){
  __shared__ float s[256];
  int t = threadIdx.x;
  float v = 0.f;
  for (int i = t; i < NN; i += 256) v += nll[i];
  s[t] = v; __syncthreads();
  for (int o = 128; o; o >>= 1){ if (t < o) s[t] += s[t + o]; __syncthreads(); }
  if (t == 0) out[0] = s[0] / (float)NN;
}

extern "C" void kernel_launch(void* const* d_in, const int* in_sizes, int n_in,
                              void* d_out, int out_size, void* d_ws, size_t ws_size,
                              hipStream_t stream) {
  const float* W   = (const float*)d_in[0];
  const float* ys  = (const float*)d_in[2];
  const int*   lab = (const int*)  d_in[3];
  const float* lam = (const float*)d_in[4];
  const float* ms  = (const float*)d_in[5];
  const float* mt  = (const float*)d_in[6];
  const float* CV  = (const float*)d_in[7];

  float* ws   = (float*)d_ws;
  float* tbl  = ws;                          // 40000
  float* accv = ws + 40000;                  // 256
  float* nll  = ws + 40256;                  // 1024
  _Float16* Whf = (_Float16*)(ws + 41280);   // 208*256 fp16
  float* out  = (float*)d_out;

  hipMemsetAsync(tbl, 0, CC * CC * sizeof(float), stream);
  k_prep <<<53, 256, 0, stream>>>(W, lab, Whf, accv);
  dim3 gq(CC, 4);
  k_quad <<<gq, 256, 0, stream>>>(Whf, CV, ms, mt, lam, tbl);
  k_rows <<<NN, 64, 0, stream>>>(ys, lab, accv, tbl, nll);
  k_mean <<<1, 256, 0, stream>>>(nll, out);
}

// Round 6
// 86.604 us; speedup vs baseline: 1.3656x; 1.2313x over previous
//
#include <hip/hip_runtime.h>
#include <hip/hip_fp16.h>
#include <math.h>

#define NN 1024
#define CC 200
#define AA 256

static constexpr float P_EXP = 0.8f;
static constexpr float Q_EXP = 2.0f;
static constexpr float EPS_C = 0.01f;

typedef __attribute__((ext_vector_type(8))) _Float16 half8;
typedef __attribute__((ext_vector_type(4))) _Float16 half4v;
typedef __attribute__((ext_vector_type(4))) float f32x4;

// ---------------- prep: W->fp16 (208 rows, zero pad) + counts ----------------
__global__ void k_prep(const float* __restrict__ W, const int* __restrict__ lab,
                       _Float16* __restrict__ Whf, float* __restrict__ accv){
  if (blockIdx.x == 52){
    __shared__ int cnt[CC];
    int t = threadIdx.x;
    for (int i = t; i < CC; i += 256) cnt[i] = 0;
    __syncthreads();
    for (int n = t; n < NN; n += 256) atomicAdd(&cnt[lab[n]], 1);
    __syncthreads();
    for (int i = t; i < CC; i += 256) accv[i] = fmaxf((float)cnt[i], 1.0f);
    return;
  }
  int idx = (blockIdx.x * 256 + threadIdx.x) * 4;
  if (idx >= 208 * AA) return;
  float4 w = make_float4(0.f, 0.f, 0.f, 0.f);
  if (idx < CC * AA) w = *(const float4*)(W + idx);
  Whf[idx + 0] = (_Float16)w.x;
  Whf[idx + 1] = (_Float16)w.y;
  Whf[idx + 2] = (_Float16)w.z;
  Whf[idx + 3] = (_Float16)w.w;
}

// ---------------- quadratic form + shift: all-MFMA, per-wave a-tile ----------------
// grid (200 l, 4 aq) x 256 (4 waves). Wave wid owns a-tile atg = aq*4+wid.
// chainA[ct] = sum_b CV_l[a,b] * W[c,b] ; accL = sum_b CV_l[a,b] * W[l,b] (bcast)
// M'[a,c] = chainA - accL.  MFMA2: diag_c( E[c',a] (M'[a,c] + 2dm bcast) ) -> tbl.
__global__ __launch_bounds__(256) void k_quad(
    const _Float16* __restrict__ Whf, const float* __restrict__ CV,
    const float* __restrict__ ms, const float* __restrict__ mtg,
    const float* __restrict__ lamp, float* __restrict__ tbl)
{
  const int l    = blockIdx.x;
  const int aq   = blockIdx.y;
  const int wid  = threadIdx.x >> 6;
  const int lane = threadIdx.x & 63;
  const int lrow = lane & 15;
  const int kgrp = lane >> 4;

  const int atg  = aq * 4 + wid;          // this wave's a-tile 0..15
  const int arow = atg * 16 + lrow;       // CV row for A1-frag

  // Wl b-frags (broadcast B for accL chain)
  half8 wl1[8];
  #pragma unroll
  for (int kt = 0; kt < 8; ++kt)
    wl1[kt] = *(const half8*)(Whf + l * AA + kt * 32 + kgrp * 8);

  // CV rows for this wave's a-tile -> fp16 A-frags (16 independent 16B loads)
  const float* cvr = CV + (size_t)l * AA * AA + (size_t)arow * AA;
  half8 cvf[8];
  #pragma unroll
  for (int kt = 0; kt < 8; ++kt){
    float4 v0 = *(const float4*)(cvr + kt * 32 + kgrp * 8);
    float4 v1 = *(const float4*)(cvr + kt * 32 + kgrp * 8 + 4);
    half8 h;
    h[0]=(_Float16)v0.x; h[1]=(_Float16)v0.y; h[2]=(_Float16)v0.z; h[3]=(_Float16)v0.w;
    h[4]=(_Float16)v1.x; h[5]=(_Float16)v1.y; h[6]=(_Float16)v1.z; h[7]=(_Float16)v1.w;
    cvf[kt] = h;
  }

  f32x4 acc1[13];
  #pragma unroll
  for (int ct = 0; ct < 13; ++ct) acc1[ct] = (f32x4){0.f, 0.f, 0.f, 0.f};
  f32x4 accL = {0.f, 0.f, 0.f, 0.f};

  // 8 + 104 MFMAs: 14 independent chains, loads interleaved
  #pragma unroll
  for (int kt = 0; kt < 8; ++kt){
    accL = __builtin_amdgcn_mfma_f32_16x16x32_f16(cvf[kt], wl1[kt], accL, 0, 0, 0);
    #pragma unroll
    for (int ct = 0; ct < 13; ++ct){
      half8 wcf = *(const half8*)(Whf + (ct * 16 + lrow) * AA + kt * 32 + kgrp * 8);
      acc1[ct] = __builtin_amdgcn_mfma_f32_16x16x32_f16(cvf[kt], wcf, acc1[ct], 0, 0, 0);
    }
  }

  // MFMA2 per ct: diag_c( E2 . (M' + 2dm) ), consumed immediately
  const int asl = atg * 16 + kgrp * 4;    // a-slice for MFMA2 K-dim
  half4v wl2 = *(const half4v*)(Whf + l * AA + asl);
  float4 dmt = *(const float4*)(mtg + l * AA + asl);
  float4 dms = *(const float4*)(ms  + l * AA + asl);
  half4v dmf;
  dmf[0] = (_Float16)(2.f * (dmt.x - dms.x));
  dmf[1] = (_Float16)(2.f * (dmt.y - dms.y));
  dmf[2] = (_Float16)(2.f * (dmt.z - dms.z));
  dmf[3] = (_Float16)(2.f * (dmt.w - dms.w));
  const float lam = lamp[0];

  #pragma unroll
  for (int ct = 0; ct < 13; ++ct){
    half4v b2;
    b2[0] = (_Float16)(acc1[ct][0] - accL[0]);
    b2[1] = (_Float16)(acc1[ct][1] - accL[1]);
    b2[2] = (_Float16)(acc1[ct][2] - accL[2]);
    b2[3] = (_Float16)(acc1[ct][3] - accL[3]);
    half4v wc2 = *(const half4v*)(Whf + (ct * 16 + lrow) * AA + asl);
    half4v e2  = wc2 - wl2;
    f32x4 d2 = {0.f, 0.f, 0.f, 0.f};
    d2 = __builtin_amdgcn_mfma_f32_16x16x16f16(e2, dmf, d2, 0, 0, 0);
    d2 = __builtin_amdgcn_mfma_f32_16x16x16f16(e2, b2,  d2, 0, 0, 0);
    const int c = ct * 16 + lrow;
    if (c < CC && (lrow >> 2) == kgrp){
      const int jj = lrow & 3;
      float d = (jj == 0) ? d2[0] : (jj == 1) ? d2[1] : (jj == 2) ? d2[2] : d2[3];
      atomicAdd(&tbl[l * CC + c], 0.5f * lam * d);
    }
  }
}

// ---------------- per-row seesaw loss ----------------
__global__ __launch_bounds__(64) void k_rows(
    const float* __restrict__ ys, const int* __restrict__ lab,
    const float* __restrict__ accv, const float* __restrict__ tbl,
    float* __restrict__ nll)
{
  const int n    = blockIdx.x;
  const int lane = threadIdx.x;
  const int l    = lab[n];
  const float acc_l = accv[l];
  const float log_acc_l = logf(acc_l);

  float z[4];
  float m = -1e30f;
  #pragma unroll
  for (int k = 0; k < 4; k++){
    int cidx = k * 64 + lane;
    float zz = (cidx < CC) ? (ys[n * CC + cidx] + tbl[l * CC + cidx]) : -1e30f;
    z[k] = zz;
    m = fmaxf(m, zz);
  }
  for (int o = 32; o; o >>= 1) m = fmaxf(m, __shfl_xor(m, o));

  float se = 0.f;
  #pragma unroll
  for (int k = 0; k < 4; k++){
    int cidx = k * 64 + lane;
    if (cidx < CC) se += expf(z[k] - m);
  }
  for (int o = 32; o; o >>= 1) se += __shfl_xor(se, o);
  const float L0 = m + logf(se);

  const int kl = l >> 6, ll = l & 63;
  float zsel = (kl == 0) ? z[0] : (kl == 1 ? z[1] : (kl == 2 ? z[2] : z[3]));
  const float zl = __shfl(zsel, ll);
  const float logden = fmaxf(zl - L0, logf(EPS_C));

  float lg[4];
  float m2 = -1e30f;
  #pragma unroll
  for (int k = 0; k < 4; k++){
    int cidx = k * 64 + lane;
    float lz = -1e30f;
    if (cidx < CC){
      lz = z[k];
      if (cidx != l){
        float lratio = (z[k] - L0) - logden;
        float lcomp  = (lratio > 0.f) ? Q_EXP * lratio : 0.f;
        float accc   = accv[cidx];
        float lmit   = (accc < acc_l) ? P_EXP * (logf(accc) - log_acc_l) : 0.f;
        lz += lcomp + lmit;
      }
    }
    lg[k] = lz;
    m2 = fmaxf(m2, lz);
  }
  for (int o = 32; o; o >>= 1) m2 = fmaxf(m2, __shfl_xor(m2, o));
  float se2 = 0.f;
  #pragma unroll
  for (int k = 0; k < 4; k++){
    int cidx = k * 64 + lane;
    if (cidx < CC) se2 += expf(lg[k] - m2);
  }
  for (int o = 32; o; o >>= 1) se2 += __shfl_xor(se2, o);
  const float L1 = m2 + logf(se2);

  if (lane == 0) nll[n] = L1 - zl;
}

// ---------------- mean ----------------
__global__ void k_mean(const float* __restrict__ nll, float* __restrict__ out){
  __shared__ float s[256];
  int t = threadIdx.x;
  float v = 0.f;
  for (int i = t; i < NN; i += 256) v += nll[i];
  s[t] = v; __syncthreads();
  for (int o = 128; o; o >>= 1){ if (t < o) s[t] += s[t + o]; __syncthreads(); }
  if (t == 0) out[0] = s[0] / (float)NN;
}

extern "C" void kernel_launch(void* const* d_in, const int* in_sizes, int n_in,
                              void* d_out, int out_size, void* d_ws, size_t ws_size,
                              hipStream_t stream) {
  const float* W   = (const float*)d_in[0];
  const float* ys  = (const float*)d_in[2];
  const int*   lab = (const int*)  d_in[3];
  const float* lam = (const float*)d_in[4];
  const float* ms  = (const float*)d_in[5];
  const float* mt  = (const float*)d_in[6];
  const float* CV  = (const float*)d_in[7];

  float* ws   = (float*)d_ws;
  float* tbl  = ws;                          // 40000
  float* accv = ws + 40000;                  // 256
  float* nll  = ws + 40256;                  // 1024
  _Float16* Whf = (_Float16*)(ws + 41280);   // 208*256 fp16
  float* out  = (float*)d_out;

  hipMemsetAsync(tbl, 0, CC * CC * sizeof(float), stream);
  k_prep <<<53, 256, 0, stream>>>(W, lab, Whf, accv);
  dim3 gq(CC, 4);
  k_quad <<<gq, 256, 0, stream>>>(Whf, CV, ms, mt, lam, tbl);
  k_rows <<<NN, 64, 0, stream>>>(ys, lab, accv, tbl, nll);
  k_mean <<<1, 256, 0, stream>>>(nll, out);
}